// Round 12
// baseline (114.899 us; speedup 1.0000x reference)
//
#include <hip/hip_runtime.h>

// MMD loss. N=8192 rows (4096 X + 4096 Y), D=64, f32 in, f32 scalar out.
//   bandwidth: closed form  sum_ij L2 = 2N*sum(sq) - 2*||sum z||^2  (cs computed
//              by last-finishing k_prep block)
//   symmetry: block-upper-triangle over 128x128 macro tiles (NBLK=64, 2080 tiles),
//             off-diag weight 2.
//   dot in pure bf16 MFMA 16x16x32; x4 = s4*L2; K5 = v+v^2+v^4+v^8+v^16, v=2^min(x4,0)
//   out = (sum_ij s_i s_j K5_ij)/4096^2, finalized by last k_main block (binned f64).

#define NX 4096
#define NT 8192
#define DD 64
#define NBLK 64
#define NTRI (NBLK * (NBLK + 1) / 2)   // 2080
#define NBIN 32
#define BINSTRIDE 8                     // doubles; 64B cache-line stride

using f32x4 = __attribute__((ext_vector_type(4))) float;
using s8v   = __attribute__((ext_vector_type(8))) short;   // 8 bf16 = 4 VGPR

__device__ __forceinline__ float fast_exp2(float x) {
#if __has_builtin(__builtin_amdgcn_exp2f)
    return __builtin_amdgcn_exp2f(x);
#else
    return exp2f(x);
#endif
}
__device__ __forceinline__ ushort f2bf(float f) {          // RTNE f32 -> bf16 bits
    unsigned u = __float_as_uint(f);
    unsigned r = u + 0x7fffu + ((u >> 16) & 1u);
    return (ushort)(r >> 16);
}

// ---- prep: bf16 cast, sq[], colsum[64], sumsq, cs[2] -- 64 blocks x 512 ----
__global__ __launch_bounds__(512)
void k_prep(const float* __restrict__ X, const float* __restrict__ Y,
            ushort* __restrict__ ZH, float* __restrict__ sq,
            float* __restrict__ colsum, double* __restrict__ sumsq,
            unsigned* __restrict__ prepcnt, float* __restrict__ cs)
{
    __shared__ float  colred[64];
    __shared__ double ssred[8];
    const int tid = threadIdx.x, bid = blockIdx.x;
    const int sub = tid & 15;
    if (tid < 64) colred[tid] = 0.f;
    __syncthreads();

    float ca0 = 0.f, ca1 = 0.f, ca2 = 0.f, ca3 = 0.f, ssq = 0.f;
#pragma unroll
    for (int k = 0; k < 4; ++k) {
        const int row = bid * 128 + k * 32 + (tid >> 4);
        const float4* zr = (const float4*)((row < NX) ? (X + (size_t)row * DD)
                                                      : (Y + (size_t)(row - NX) * DD));
        float4 v = zr[sub];
        ((ushort4*)(ZH + (size_t)row * DD))[sub] =
            make_ushort4(f2bf(v.x), f2bf(v.y), f2bf(v.z), f2bf(v.w));
        float d = fmaf(v.x, v.x, fmaf(v.y, v.y, fmaf(v.z, v.z, v.w * v.w)));
        ssq += d;
        float dr = d;
#pragma unroll
        for (int m = 1; m < 16; m <<= 1) dr += __shfl_xor(dr, m);
        if (sub == 0) sq[row] = dr;
        ca0 += v.x; ca1 += v.y; ca2 += v.z; ca3 += v.w;
    }

    // column sums within wave: lanes {l, l+16, l+32, l+48} share sub
    ca0 += __shfl_xor(ca0, 16); ca0 += __shfl_xor(ca0, 32);
    ca1 += __shfl_xor(ca1, 16); ca1 += __shfl_xor(ca1, 32);
    ca2 += __shfl_xor(ca2, 16); ca2 += __shfl_xor(ca2, 32);
    ca3 += __shfl_xor(ca3, 16); ca3 += __shfl_xor(ca3, 32);
    if ((tid & 63) < 16) {
        atomicAdd(&colred[sub * 4 + 0], ca0);
        atomicAdd(&colred[sub * 4 + 1], ca1);
        atomicAdd(&colred[sub * 4 + 2], ca2);
        atomicAdd(&colred[sub * 4 + 3], ca3);
    }
#pragma unroll
    for (int off = 32; off; off >>= 1) ssq += __shfl_down(ssq, off);
    if ((tid & 63) == 0) ssred[tid >> 6] = (double)ssq;
    __syncthreads();
    if (tid == 0) {
        double s = 0.0;
#pragma unroll
        for (int w = 0; w < 8; ++w) s += ssred[w];
        atomicAdd(sumsq, s);
    }
    if (tid < 64) atomicAdd(&colsum[tid], colred[tid]);

    // last-finishing block computes the bandwidth constants
    __threadfence();
    __syncthreads();
    if (tid == 0) {
        if (atomicAdd(prepcnt, 1u) == 63u) {
            double s2 = 0.0;
            for (int c = 0; c < 64; ++c) { double v = (double)colsum[c]; s2 += v * v; }
            double sl2 = 2.0 * (double)NT * sumsq[0] - 2.0 * s2;
            double bw  = sl2 / ((double)NT * (double)NT - (double)NT);
            double s4  = -0.36067376022224085 / bw;    // -log2(e)/4 / bw
            cs[0] = (float)s4;
            cs[1] = (float)(-2.0 * s4);
        }
    }
}

// ---- main pairwise pass (block-upper-triangle, 128x128 tiles) --------------
// grid 2080 x 256 threads (4 waves). Wave w: rows rbase=bi*128+w*32 (rg 0..1),
// 4 j-steps of 32 cols. Per step: 8 MFMA + 16 K5 evals/lane.
struct BFrag { s8v h[2][2]; };   // [cg][ks]

__global__ __launch_bounds__(256, 5)   // cap ~102 VGPR -> ~5 blocks/CU
void k_main(const ushort* __restrict__ ZH, const float* __restrict__ sq,
            const float* __restrict__ cs,
            double* __restrict__ accbin, unsigned* __restrict__ cnt,
            float* __restrict__ out)
{
    __shared__ double sred[4];
    const int tid = threadIdx.x, lane = tid & 63, wid = tid >> 6;
    const int l15 = lane & 15, lh = lane >> 4;

    // triangle decode: offset(bi) = bi*(129-bi)/2
    const int t = blockIdx.x;
    int bi = (int)((129.0 - __builtin_sqrt(16641.0 - 8.0 * (double)t)) * 0.5);
    while (bi * (129 - bi) / 2 > t) --bi;
    while ((bi + 1) * (129 - (bi + 1)) / 2 <= t) ++bi;
    const int bj = bi + (t - bi * (129 - bi) / 2);

    const int rbase = bi * 128 + wid * 32;
    const int jbase = bj * 128;
    const float s4 = cs[0], c2q = cs[1];

    // A fragments + row-norm terms + all j-step norm scalars, prefetched
    s8v ah[2][2];
    f32x4 psi[2];
#pragma unroll
    for (int rg = 0; rg < 2; ++rg) {
#pragma unroll
        for (int ks = 0; ks < 2; ++ks)
            ah[rg][ks] = *(const s8v*)(ZH + (size_t)(rbase + rg * 16 + l15) * DD + ks * 32 + lh * 8);
        psi[rg] = s4 * (*(const f32x4*)(sq + rbase + rg * 16 + lh * 4));
    }
    float sjv[4][2];
#pragma unroll
    for (int tt = 0; tt < 4; ++tt) {
        sjv[tt][0] = s4 * sq[jbase + tt * 32 + l15];
        sjv[tt][1] = s4 * sq[jbase + tt * 32 + 16 + l15];
    }

    double dsum = 0.0;

    auto LOADB = [&](BFrag& b, int tt) {
        const int cb = jbase + tt * 32;
#pragma unroll
        for (int cg = 0; cg < 2; ++cg)
#pragma unroll
            for (int ks = 0; ks < 2; ++ks)
                b.h[cg][ks] = *(const s8v*)(ZH + (size_t)(cb + cg * 16 + l15) * DD + ks * 32 + lh * 8);
    };

    auto STEP = [&](const BFrag& b, int tt) {
        f32x4 acc[2][2];
#pragma unroll
        for (int rg = 0; rg < 2; ++rg)
#pragma unroll
            for (int cg = 0; cg < 2; ++cg)
                acc[rg][cg] = (f32x4){0.f, 0.f, 0.f, 0.f};
#pragma unroll
        for (int ks = 0; ks < 2; ++ks)
#pragma unroll
            for (int rg = 0; rg < 2; ++rg)
#pragma unroll
                for (int cg = 0; cg < 2; ++cg)
                    acc[rg][cg] = __builtin_amdgcn_mfma_f32_16x16x32_bf16(
                        ah[rg][ks], b.h[cg][ks], acc[rg][cg], 0, 0, 0);
        float bsum = 0.f;
#pragma unroll
        for (int rg = 0; rg < 2; ++rg)
#pragma unroll
            for (int cg = 0; cg < 2; ++cg) {
                const float sj = sjv[tt][cg];
#pragma unroll
                for (int q = 0; q < 4; ++q) {
                    float x = fmaf(c2q, acc[rg][cg][q], psi[rg][q] + sj);
                    x = fminf(x, 0.f);              // clamp(L2,0)
                    float v  = fast_exp2(x);        // u^(1/4)
                    float v2 = v * v, v4 = v2 * v2, v8 = v4 * v4, v16 = v8 * v8;
                    bsum += ((v16 + v8) + (v4 + v2)) + v;
                }
            }
        dsum += (double)bsum;
    };

    BFrag b0, b1;
    LOADB(b0, 0);
    LOADB(b1, 1);
    STEP(b0, 0);
    LOADB(b0, 2);
    STEP(b1, 1);
    LOADB(b1, 3);
    STEP(b0, 2);
    STEP(b1, 3);

#pragma unroll
    for (int off = 32; off; off >>= 1) dsum += __shfl_down(dsum, off);
    if (lane == 0) sred[wid] = dsum;
    __syncthreads();
    if (tid == 0) {
        double bsum = sred[0] + sred[1] + sred[2] + sred[3];
        const bool pos = (bi < 32) == (bj < 32);    // sign s_i*s_j, tile-uniform
        const double wt = (bi == bj) ? 1.0 : 2.0;   // triangle weight
        atomicAdd(&accbin[(blockIdx.x & (NBIN - 1)) * BINSTRIDE],
                  pos ? wt * bsum : -wt * bsum);
        __threadfence();
        unsigned old = atomicAdd(cnt, 1u);
        if (old == (unsigned)NTRI - 1u) {           // last block finalizes
            double S = 0.0;
            for (int bq = 0; bq < NBIN; ++bq) S += accbin[bq * BINSTRIDE];
            out[0] = (float)(S * (1.0 / ((double)NX * (double)NX)));
        }
    }
}

extern "C" void kernel_launch(void* const* d_in, const int* in_sizes, int n_in,
                              void* d_out, int out_size, void* d_ws, size_t ws_size,
                              hipStream_t stream)
{
    const float* X = (const float*)d_in[0];
    const float* Y = (const float*)d_in[1];

    char* ws = (char*)d_ws;
    double*   sumsq   = (double*)(ws + 0);
    unsigned* cnt     = (unsigned*)(ws + 16);
    unsigned* prepcnt = (unsigned*)(ws + 20);
    float*    cs      = (float*)(ws + 24);              // 2 f32
    float*    colsum  = (float*)(ws + 64);              // 64 f32
    double*   accbin  = (double*)(ws + 512);            // 32 bins x 64B
    float*    sq      = (float*)(ws + 4096);            // 8192 f32
    ushort*   ZH      = (ushort*)(ws + 65536);          // 1 MB

    hipMemsetAsync(d_ws, 0, 4096, stream);
    k_prep<<<64, 512, 0, stream>>>(X, Y, ZH, sq, colsum, sumsq, prepcnt, cs);
    k_main<<<NTRI, 256, 0, stream>>>(ZH, sq, cs, accbin, cnt, (float*)d_out);
}